// Round 1
// baseline (75.803 us; speedup 1.0000x reference)
//
#include <hip/hip_runtime.h>

// GNNEmbeds: 3-layer NNConv (ECConv) with scalar edge features.
// Key identity: W(e) = attr_e * A + B  (A = lin_w.reshape(in,out), B = lin_b.reshape(in,out))
//  => msg_e = attr_e * (h[src] @ A) + (h[src] @ B)
// Per layer: U = h@A, V = h@B, agg = h@root + bias; then agg[dst] += attr*U[src]+V[src].
// N=1024, E=8192, IN=2, H=OUT=128 (N,E derived from in_sizes).

#define HD 128   // hidden/out dim

// ---- Layer 1: in_c = 2, compute U1,V1 and agg-init in one tiny kernel ----
__global__ __launch_bounds__(128) void layer1_kernel(
    const float* __restrict__ x, const float* __restrict__ lw,
    const float* __restrict__ lb, const float* __restrict__ root,
    const float* __restrict__ bias,
    float* __restrict__ U, float* __restrict__ V, float* __restrict__ AGG)
{
    const int n = blockIdx.x;
    const int o = threadIdx.x;
    const float x0 = x[n * 2 + 0];
    const float x1 = x[n * 2 + 1];
    U[n * HD + o]   = fmaf(x0, lw[o],   x1 * lw[HD + o]);
    V[n * HD + o]   = fmaf(x0, lb[o],   x1 * lb[HD + o]);
    AGG[n * HD + o] = fmaf(x0, root[o], fmaf(x1, root[HD + o], bias[o]));
}

// ---- Edge scatter: agg[dst] += attr_e * U[src] + V[src], 32 lanes/edge x float4 ----
__global__ __launch_bounds__(256) void edge_scatter(
    const int* __restrict__ ei, const float* __restrict__ attr,
    const float* __restrict__ U, const float* __restrict__ V,
    float* __restrict__ AGG, int E)
{
    const int tid = blockIdx.x * 256 + threadIdx.x;
    const int e = tid >> 5;
    if (e >= E) return;
    const int c = (tid & 31) << 2;
    const int s = ei[e];        // src row (edge_index[0][e])
    const int d = ei[E + e];    // dst row (edge_index[1][e])
    const float a = attr[e];
    const float4 u = *(const float4*)(U + s * HD + c);
    const float4 v = *(const float4*)(V + s * HD + c);
    float* p = AGG + d * HD + c;
    atomicAdd(p + 0, fmaf(a, u.x, v.x));
    atomicAdd(p + 1, fmaf(a, u.y, v.y));
    atomicAdd(p + 2, fmaf(a, u.z, v.z));
    atomicAdd(p + 3, fmaf(a, u.w, v.w));
}

// ---- Fused 3-matrix GEMM for layers 2/3: out{U,V,AGG} = relu(h) @ {A,B,root},
//      AGG additionally gets +bias. Block: 32 rows x 128 cols, 4x4 reg tile. ----
__global__ __launch_bounds__(256) void gemm3_kernel(
    const float* __restrict__ h,
    const float* __restrict__ Wa, const float* __restrict__ Wb,
    const float* __restrict__ Wr, const float* __restrict__ bias,
    float* __restrict__ U, float* __restrict__ V, float* __restrict__ AGG)
{
    __shared__ float hs[32][HD];
    const int t = threadIdx.x;
    const int n0 = blockIdx.x * 32;

    // Stage relu(h) tile: 32x128 floats = 1024 float4, 4 per thread, coalesced.
    float4* hsv = (float4*)&hs[0][0];
    const float4* hv = (const float4*)(h + n0 * HD);
#pragma unroll
    for (int i = 0; i < 4; ++i) {
        float4 val = hv[t + 256 * i];
        val.x = fmaxf(val.x, 0.f); val.y = fmaxf(val.y, 0.f);
        val.z = fmaxf(val.z, 0.f); val.w = fmaxf(val.w, 0.f);
        hsv[t + 256 * i] = val;
    }
    __syncthreads();

    const float* W; float* O;
    if      (blockIdx.y == 0) { W = Wa; O = U; }
    else if (blockIdx.y == 1) { W = Wb; O = V; }
    else                      { W = Wr; O = AGG; }

    const int colg = (t & 31) << 2;  // 4 contiguous cols
    const int rowg = (t >> 5) << 2;  // 4 rows

    float acc[4][4];
#pragma unroll
    for (int r = 0; r < 4; ++r)
#pragma unroll
        for (int c = 0; c < 4; ++c) acc[r][c] = 0.f;

#pragma unroll 4
    for (int k = 0; k < HD; ++k) {
        const float4 w = *(const float4*)(W + k * HD + colg);
#pragma unroll
        for (int r = 0; r < 4; ++r) {
            const float hr = hs[rowg + r][k];   // 2-way LDS alias per wave: free
            acc[r][0] = fmaf(hr, w.x, acc[r][0]);
            acc[r][1] = fmaf(hr, w.y, acc[r][1]);
            acc[r][2] = fmaf(hr, w.z, acc[r][2]);
            acc[r][3] = fmaf(hr, w.w, acc[r][3]);
        }
    }

    float4 b = make_float4(0.f, 0.f, 0.f, 0.f);
    if (blockIdx.y == 2) b = *(const float4*)(bias + colg);
#pragma unroll
    for (int r = 0; r < 4; ++r) {
        float4 o;
        o.x = acc[r][0] + b.x; o.y = acc[r][1] + b.y;
        o.z = acc[r][2] + b.z; o.w = acc[r][3] + b.w;
        *(float4*)(O + (n0 + rowg + r) * HD + colg) = o;
    }
}

extern "C" void kernel_launch(void* const* d_in, const int* in_sizes, int n_in,
                              void* d_out, int out_size, void* d_ws, size_t ws_size,
                              hipStream_t stream) {
    const float* x     = (const float*)d_in[0];
    const int*   ei    = (const int*)  d_in[1];
    const float* attr  = (const float*)d_in[2];
    const float* lw1   = (const float*)d_in[3];
    const float* lb1   = (const float*)d_in[4];
    const float* root1 = (const float*)d_in[5];
    const float* bias1 = (const float*)d_in[6];
    const float* lw2   = (const float*)d_in[7];
    const float* lb2   = (const float*)d_in[8];
    const float* root2 = (const float*)d_in[9];
    const float* bias2 = (const float*)d_in[10];
    const float* lw3   = (const float*)d_in[11];
    const float* lb3   = (const float*)d_in[12];
    const float* root3 = (const float*)d_in[13];
    const float* bias3 = (const float*)d_in[14];

    const int N = in_sizes[0] / 2;   // x is [N, 2]
    const int E = in_sizes[1] / 2;   // edge_index is [2, E]

    float* out = (float*)d_out;
    float* ws  = (float*)d_ws;
    float* U  = ws;                  // [N, 128]
    float* V  = ws + (size_t)N * HD; // [N, 128]
    float* A1 = ws + (size_t)2 * N * HD;
    float* A2 = ws + (size_t)3 * N * HD;

    const int eblocks = (E * 32 + 255) / 256;
    const dim3 gblocks(N / 32, 3);

    // Layer 1
    layer1_kernel<<<N, 128, 0, stream>>>(x, lw1, lb1, root1, bias1, U, V, A1);
    edge_scatter<<<eblocks, 256, 0, stream>>>(ei, attr, U, V, A1, E);
    // Layer 2 (relu of A1 applied inside gemm3)
    gemm3_kernel<<<gblocks, 256, 0, stream>>>(A1, lw2, lb2, root2, bias2, U, V, A2);
    edge_scatter<<<eblocks, 256, 0, stream>>>(ei, attr, U, V, A2, E);
    // Layer 3 (no relu on output)
    gemm3_kernel<<<gblocks, 256, 0, stream>>>(A2, lw3, lb3, root3, bias3, U, V, out);
    edge_scatter<<<eblocks, 256, 0, stream>>>(ei, attr, U, V, out, E);
}